// Round 9
// baseline (98.626 us; speedup 1.0000x reference)
//
#include <hip/hip_runtime.h>
#include <hip/hip_bf16.h>
#include <stdint.h>

// Problem: B=16, S=1024, IN=1024, OUT=1024.
// Reference collapses: softmax row-sums are exactly 1 (key mask always has >=1
// live column), so out = leaky_relu(xs @ (Wlin@Wv)^T + (Wlin@bv + blin)).
//
// Round 9: abandon 256x256/1-block-per-CU (barrier-stall-bound, rounds 4-8
// all 440-690 TF). m97 regime instead: 128x128, BK=32, 256 threads, 16KB LDS,
// plain 2-barrier loop, ~3 blocks/CU for cross-block latency hiding — PLUS
// the swizzled LDS that rounds 1-2 lacked (their 4.2M 8-way conflicts were
// the gap). A fused fp32->bf16 (reg cvt + linear ds_write, inverse-swizzled
// content); B via pre-swizzled-source global_load_lds.

#define M_TOT 16384   // B*S
#define KDIM  1024
#define NDIM  1024

typedef __attribute__((ext_vector_type(8))) short bf16x8;
typedef __attribute__((ext_vector_type(4))) float f32x4;
typedef __attribute__((ext_vector_type(4))) unsigned short u16x4;
typedef __attribute__((ext_vector_type(8))) unsigned short u16x8;

static __device__ __forceinline__ unsigned short f2bf(float f) {
    union { float f; unsigned int u; } v; v.f = f;
    unsigned int u = v.u;
    return (unsigned short)((u + 0x7fffu + ((u >> 16) & 1u)) >> 16);  // RNE
}

static __device__ __forceinline__ u16x8 pack8(float4 a, float4 b) {
    u16x8 p = { f2bf(a.x), f2bf(a.y), f2bf(a.z), f2bf(a.w),
                f2bf(b.x), f2bf(b.y), f2bf(b.z), f2bf(b.w) };
    return p;
}

static __device__ __forceinline__ void gload16(const void* g, void* l) {
    __builtin_amdgcn_global_load_lds(
        (__attribute__((address_space(1))) void*)(g),
        (__attribute__((address_space(3))) void*)(l), 16, 0, 0);
}

// Involutive LDS byte-swizzle within each 1KB subtile of a [rows][32]bf16
// (64B-stride) region: XOR row bits (p8,p9) into 16B-slot bits (4,5).
// Read conflict drops 8-way -> 2-way (free, m136).
static __device__ __forceinline__ int swz(int p) {
    return p ^ (((p >> 9) & 1) << 5) ^ (((p >> 8) & 1) << 4);
}

// ---------------------------------------------------------------------------
// prep0: [0,256) transpose Wv[d][i] -> Wvt[i][d] bf16 (64x64 tiles, padded
//        fp32 LDS); [256,512) Wlin -> Wlb bf16; [512,768) bias fold.
// ---------------------------------------------------------------------------
__global__ __launch_bounds__(256) void prep0_kernel(
    const float* __restrict__ Wv, const float* __restrict__ Wlin,
    const float* __restrict__ bv, const float* __restrict__ blin,
    unsigned short* __restrict__ Wvt, unsigned short* __restrict__ Wlb,
    float* __restrict__ bcomb) {
    __shared__ float Tl[64 * 65];
    const int bid = blockIdx.x;
    const int t = threadIdx.x;

    if (bid < 256) {
        const int dt = bid >> 4;
        const int it = bid & 15;
        const int r = t >> 2;
        const int c0 = (t & 3) * 16;
        #pragma unroll
        for (int u = 0; u < 4; ++u) {
            float4 v = *(const float4*)&Wv[((size_t)(dt * 64 + r)) * NDIM + it * 64 + c0 + 4 * u];
            Tl[r * 65 + c0 + 4 * u + 0] = v.x;
            Tl[r * 65 + c0 + 4 * u + 1] = v.y;
            Tl[r * 65 + c0 + 4 * u + 2] = v.z;
            Tl[r * 65 + c0 + 4 * u + 3] = v.w;
        }
        __syncthreads();
        const int i = t >> 2;
        const int dq = (t & 3) * 16;
        float v[16];
        #pragma unroll
        for (int u = 0; u < 16; ++u) v[u] = Tl[(dq + u) * 65 + i];
        u16x8 p0 = { f2bf(v[0]), f2bf(v[1]), f2bf(v[2]), f2bf(v[3]),
                     f2bf(v[4]), f2bf(v[5]), f2bf(v[6]), f2bf(v[7]) };
        u16x8 p1 = { f2bf(v[8]), f2bf(v[9]), f2bf(v[10]), f2bf(v[11]),
                     f2bf(v[12]), f2bf(v[13]), f2bf(v[14]), f2bf(v[15]) };
        unsigned short* dst = &Wvt[((size_t)(it * 64 + i)) * KDIM + dt * 64 + dq];
        *(u16x8*)dst = p0;
        *(u16x8*)(dst + 8) = p1;
    } else if (bid < 512) {
        const size_t idx = (((size_t)(bid - 256)) * 256 + t) * 16;
        float4 a = *(const float4*)&Wlin[idx];
        float4 b = *(const float4*)&Wlin[idx + 4];
        float4 c = *(const float4*)&Wlin[idx + 8];
        float4 d = *(const float4*)&Wlin[idx + 12];
        *(u16x8*)&Wlb[idx] = pack8(a, b);
        *(u16x8*)&Wlb[idx + 8] = pack8(c, d);
    } else {
        const int wave = t >> 6, lane = t & 63;
        const int o = (bid - 512) * 4 + wave;
        float s = 0.f;
        for (int d = lane; d < KDIM; d += 64) s += Wlin[o * KDIM + d] * bv[d];
        #pragma unroll
        for (int off = 32; off > 0; off >>= 1) s += __shfl_down(s, off, 64);
        if (lane == 0) bcomb[o] = s + blin[o];
    }
}

// ---------------------------------------------------------------------------
// wcomb: Wc[o][i] = sum_d Wlb[o][d] * Wvt[i][d]. 64x64 tiles, 256 blocks,
// 4 waves (2x2 of 32x32), both operands via global_load_lds.
// ---------------------------------------------------------------------------
__global__ __launch_bounds__(256) void wcomb_kernel(
    const unsigned short* __restrict__ Wlb, const unsigned short* __restrict__ Wvt,
    unsigned short* __restrict__ Wc) {
    __shared__ unsigned short As[64 * 32];
    __shared__ unsigned short Bs[64 * 32];
    const int t = threadIdx.x;
    const int ot = blockIdx.x >> 4;
    const int it = blockIdx.x & 15;
    const int w = t >> 6, l = t & 63;
    const int wr = (w >> 1) * 32, wc = (w & 1) * 32;
    const int lr = l & 15, lk = l >> 4;

    f32x4 acc[2][2] = {};

    const unsigned short* gA = &Wlb[((size_t)(ot * 64 + (t >> 2))) * KDIM + (t & 3) * 8];
    const unsigned short* gB = &Wvt[((size_t)(it * 64 + (t >> 2))) * KDIM + (t & 3) * 8];
    unsigned short* lA = &As[w * 512];
    unsigned short* lB = &Bs[w * 512];

    for (int kt = 0; kt < KDIM / 32; ++kt) {
        gload16(gA + kt * 32, lA);
        gload16(gB + kt * 32, lB);
        __syncthreads();
        bf16x8 af[2], bfr[2];
        #pragma unroll
        for (int fi = 0; fi < 2; ++fi)
            af[fi] = *(bf16x8*)&As[(wr + fi * 16 + lr) * 32 + lk * 8];
        #pragma unroll
        for (int fj = 0; fj < 2; ++fj)
            bfr[fj] = *(bf16x8*)&Bs[(wc + fj * 16 + lr) * 32 + lk * 8];
        #pragma unroll
        for (int fi = 0; fi < 2; ++fi)
            #pragma unroll
            for (int fj = 0; fj < 2; ++fj)
                acc[fi][fj] = __builtin_amdgcn_mfma_f32_16x16x32_bf16(
                    af[fi], bfr[fj], acc[fi][fj], 0, 0, 0);
        __syncthreads();
    }
    #pragma unroll
    for (int fi = 0; fi < 2; ++fi)
        #pragma unroll
        for (int fj = 0; fj < 2; ++fj)
            #pragma unroll
            for (int r = 0; r < 4; ++r) {
                const int o = ot * 64 + wr + fi * 16 + lk * 4 + r;
                const int i = it * 64 + wc + fj * 16 + lr;
                Wc[(size_t)o * KDIM + i] = f2bf(acc[fi][fj][r]);
            }
}

// ---------------------------------------------------------------------------
// main_fused: out = leaky(bf16(xs) @ Wc^T + bcomb), fp32 A converted in-kernel.
// m97 regime: BM=BN=128, BK=32, 4 waves (2x2 of 64x64), 16KB static LDS,
// single-buffered 2-barrier loop, ~3 blocks/CU for cross-block overlap.
// As/Bs are swizzled [128][32]bf16 tiles (2-way residual conflicts only).
// A: 4 float4 xs loads -> cvt -> 2 linear ds_write (content inverse-swizzled).
// B: 2 global_load_lds from pre-swizzled source. Grid 1024, XCD swizzle.
// ---------------------------------------------------------------------------
__global__ __launch_bounds__(256) void main_fused(
    const float* __restrict__ xs, const unsigned short* __restrict__ Wc,
    const float* __restrict__ bcomb, float* __restrict__ out) {
    __shared__ __align__(16) char As[8192];
    __shared__ __align__(16) char Bs[8192];
    const int t = threadIdx.x;
    const int w = t >> 6, l = t & 63;
    const int wm = w >> 1, wn = w & 1;
    const int lr = l & 15, lk = l >> 4;

    // XCD swizzle: bijective (1024 % 8 == 0); each XCD gets 16 consecutive
    // mt panels x all nt -> A-panel L2 reuse.
    const int swzb = ((blockIdx.x & 7) << 7) + (blockIdx.x >> 3);
    const int mt = swzb >> 3, nt = swzb & 7;

    // reader byte offsets (swizzled)
    int aoff[4], boff[4];
    #pragma unroll
    for (int fi = 0; fi < 4; ++fi)
        aoff[fi] = swz((wm * 64 + fi * 16 + lr) * 64 + lk * 16);
    #pragma unroll
    for (int fj = 0; fj < 4; ++fj)
        boff[fj] = swz((wn * 64 + fj * 16 + lr) * 64 + lk * 16);

    // staging: linear LDS byte q holds logical tile byte p = swz(q).
    // A (fp32 source): thread t covers q = c*4096 + t*16, c in {0,1}.
    const float* gAq[2];
    #pragma unroll
    for (int c = 0; c < 2; ++c) {
        const int q = c * 4096 + t * 16;
        const int p = swz(q);
        gAq[c] = xs + ((size_t)(mt * 128 + (p >> 6))) * KDIM + ((p & 63) >> 1);
    }
    // B (bf16 source, gload_lds): wave w covers q = c*4096 + w*1024 + l*16.
    const char* gBq[2];
    #pragma unroll
    for (int c = 0; c < 2; ++c) {
        const int q = c * 4096 + w * 1024 + l * 16;
        const int p = swz(q);
        gBq[c] = (const char*)Wc + ((size_t)(nt * 128 + (p >> 6))) * 2048 + (p & 63);
    }

    f32x4 acc[4][4] = {};

    for (int kt = 0; kt < KDIM / 32; ++kt) {
        // stage: A fp32 -> regs, B -> LDS, cvt A -> LDS (linear dests)
        float4 a0 = *(const float4*)(gAq[0] + kt * 32);
        float4 a1 = *(const float4*)(gAq[0] + kt * 32 + 4);
        float4 a2 = *(const float4*)(gAq[1] + kt * 32);
        float4 a3 = *(const float4*)(gAq[1] + kt * 32 + 4);
        gload16(gBq[0] + (size_t)kt * 64, Bs + w * 1024);
        gload16(gBq[1] + (size_t)kt * 64, Bs + 4096 + w * 1024);
        *(u16x8*)(As + t * 16) = pack8(a0, a1);
        *(u16x8*)(As + 4096 + t * 16) = pack8(a2, a3);
        __syncthreads();  // drains vmcnt (gload_lds) + lgkm (ds_write)

        bf16x8 af[4], bfr[4];
        #pragma unroll
        for (int fi = 0; fi < 4; ++fi)
            af[fi] = *(const bf16x8*)(As + aoff[fi]);
        #pragma unroll
        for (int fj = 0; fj < 4; ++fj)
            bfr[fj] = *(const bf16x8*)(Bs + boff[fj]);
        #pragma unroll
        for (int fi = 0; fi < 4; ++fi)
            #pragma unroll
            for (int fj = 0; fj < 4; ++fj)
                acc[fi][fj] = __builtin_amdgcn_mfma_f32_16x16x32_bf16(
                    af[fi], bfr[fj], acc[fi][fj], 0, 0, 0);
        __syncthreads();  // reads done before next stage overwrites
    }

    // epilogue: + bias, leaky_relu, fp32 store
    #pragma unroll
    for (int fi = 0; fi < 4; ++fi)
        #pragma unroll
        for (int fj = 0; fj < 4; ++fj) {
            const int col = nt * 128 + wn * 64 + fj * 16 + lr;
            const float b = bcomb[col];
            #pragma unroll
            for (int r = 0; r < 4; ++r) {
                const int row = mt * 128 + wm * 64 + fi * 16 + lk * 4 + r;
                float v = acc[fi][fj][r] + b;
                out[(size_t)row * NDIM + col] = v >= 0.f ? v : 0.01f * v;
            }
        }
}

// ---------------------------------------------------------------------------
// Fallback main GEMM (fused fp32->bf16 A path, 128x128, unswizzled) if ws
// is too small for Wc+bcomb (not expected).
// ---------------------------------------------------------------------------
__global__ __launch_bounds__(256) void main_gemm_f32(
    const float* __restrict__ X, const unsigned short* __restrict__ Wc,
    const float* __restrict__ bcomb, float* __restrict__ out) {
    __shared__ unsigned short As[128 * 32];
    __shared__ unsigned short Bs[128 * 32];
    const int t = threadIdx.x;
    const int nt = blockIdx.x & 7;
    const int mt = blockIdx.x >> 3;
    const int w = t >> 6, l = t & 63;
    const int wr = (w >> 1) * 64, wcc = (w & 1) * 64;
    const int lr = l & 15, lk = l >> 4;

    f32x4 acc[4][4] = {};

    const int arow = t >> 3;
    const int akq = t & 7;
    const int brow = t >> 2;
    const int bc4 = t & 3;

    for (int kt = 0; kt < KDIM / 32; ++kt) {
        float4 av[4];
        #pragma unroll
        for (int j = 0; j < 4; ++j) {
            const int row = j * 32 + arow;
            av[j] = *(const float4*)&X[(mt * 128 + row) * KDIM + kt * 32 + akq * 4];
        }
        __syncthreads();
        #pragma unroll
        for (int j = 0; j < 4; ++j) {
            const int row = j * 32 + arow;
            u16x4 p = { f2bf(av[j].x), f2bf(av[j].y), f2bf(av[j].z), f2bf(av[j].w) };
            *(u16x4*)&As[row * 32 + akq * 4] = p;
        }
        #pragma unroll
        for (int j = 0; j < 2; ++j) {
            const int row = j * 64 + brow;
            const unsigned short* g = &Wc[(nt * 128 + row) * KDIM + kt * 32 + bc4 * 8];
            unsigned short* ldst = &Bs[(j * 256 + w * 64) * 8];
            gload16(g, ldst);
        }
        __syncthreads();
        bf16x8 af[4], bfr[4];
        #pragma unroll
        for (int fi = 0; fi < 4; ++fi)
            af[fi] = *(bf16x8*)&As[(wr + fi * 16 + lr) * 32 + lk * 8];
        #pragma unroll
        for (int fj = 0; fj < 4; ++fj)
            bfr[fj] = *(bf16x8*)&Bs[(wcc + fj * 16 + lr) * 32 + lk * 8];
        #pragma unroll
        for (int fi = 0; fi < 4; ++fi)
            #pragma unroll
            for (int fj = 0; fj < 4; ++fj)
                acc[fi][fj] = __builtin_amdgcn_mfma_f32_16x16x32_bf16(
                    af[fi], bfr[fj], acc[fi][fj], 0, 0, 0);
    }

    #pragma unroll
    for (int fi = 0; fi < 4; ++fi)
        #pragma unroll
        for (int fj = 0; fj < 4; ++fj) {
            const int col = nt * 128 + wcc + fj * 16 + lr;
            const float b = bcomb[col];
            #pragma unroll
            for (int r = 0; r < 4; ++r) {
                const int row = mt * 128 + wr + fi * 16 + lk * 4 + r;
                float v = acc[fi][fj][r] + b;
                out[row * NDIM + col] = v >= 0.f ? v : 0.01f * v;
            }
        }
}

extern "C" void kernel_launch(void* const* d_in, const int* in_sizes, int n_in,
                              void* d_out, int out_size, void* d_ws, size_t ws_size,
                              hipStream_t stream) {
    const float* xs   = (const float*)d_in[0];
    // d_in[1] mask unused: softmax row-sums are exactly 1.
    const float* Wv   = (const float*)d_in[6];
    const float* bv   = (const float*)d_in[7];
    const float* Wlin = (const float*)d_in[8];
    const float* blin = (const float*)d_in[9];

    unsigned short* Wc = (unsigned short*)d_ws;                         // 2 MB
    float* bcomb = (float*)((char*)d_ws + 2097152);                     // 4 KB
    float* out = (float*)d_out;

    // transient scratch in d_out (64 MB, fully overwritten by the final GEMM)
    unsigned short* Wvt = (unsigned short*)d_out;                       // 2 MB
    unsigned short* Wlb = (unsigned short*)((char*)d_out + 2097152);    // 2 MB

    const size_t NEED = 2101248;
    hipLaunchKernelGGL(prep0_kernel, dim3(768), dim3(256), 0, stream,
                       Wv, Wlin, bv, blin, Wvt, Wlb, bcomb);
    hipLaunchKernelGGL(wcomb_kernel, dim3(256), dim3(256), 0, stream,
                       Wlb, Wvt, Wc);
    if (ws_size >= NEED) {
        hipLaunchKernelGGL(main_fused, dim3((M_TOT / 128) * (NDIM / 128)),
                           dim3(256), 0, stream, xs, Wc, bcomb, out);
    } else {
        hipLaunchKernelGGL(main_gemm_f32, dim3((M_TOT / 128) * (NDIM / 128)),
                           dim3(256), 0, stream, xs, Wc, bcomb, out);
    }
}

// Round 10
// 74.921 us; speedup vs baseline: 1.3164x; 1.3164x over previous
//
#include <hip/hip_runtime.h>
#include <hip/hip_bf16.h>
#include <stdint.h>

// Problem: B=16, S=1024, IN=1024, OUT=1024.
// Reference collapses: softmax row-sums are exactly 1 (key mask always has >=1
// live column), so out = leaky_relu(xs @ (Wlin@Wv)^T + (Wlin@bv + blin)).
//
// Round 10: round-4's proven 256x256 4-buffer counted-vmcnt ring (best main
// GEMM this session, 50us) with the LDS geometry that measured ZERO bank
// conflicts in rounds 5-7: bf16 tiles packed as row-pairs into 128B rows
// (P(r,k) = (r>>1)*128 + (r&1)*64 + k*2) + swz128 3-bit XOR, both-sides.
// Round-4's 2-bit swizzle on 64B rows left 3.1M conflicts. Prep: prep0 + one
// dispatch of 256-block wcomb(64^2) + 2048-block xs->bf16 conversion.

#define M_TOT 16384   // B*S
#define KDIM  1024
#define NDIM  1024
#define NT    32      // K-tiles of BK=32 in main GEMM

typedef __attribute__((ext_vector_type(8))) short bf16x8;
typedef __attribute__((ext_vector_type(4))) float f32x4;
typedef __attribute__((ext_vector_type(4))) unsigned short u16x4;
typedef __attribute__((ext_vector_type(8))) unsigned short u16x8;

static __device__ __forceinline__ unsigned short f2bf(float f) {
    union { float f; unsigned int u; } v; v.f = f;
    unsigned int u = v.u;
    return (unsigned short)((u + 0x7fffu + ((u >> 16) & 1u)) >> 16);  // RNE
}

static __device__ __forceinline__ u16x8 pack8(float4 a, float4 b) {
    u16x8 p = { f2bf(a.x), f2bf(a.y), f2bf(a.z), f2bf(a.w),
                f2bf(b.x), f2bf(b.y), f2bf(b.z), f2bf(b.w) };
    return p;
}

static __device__ __forceinline__ void gload16(const void* g, void* l) {
    __builtin_amdgcn_global_load_lds(
        (__attribute__((address_space(1))) void*)(g),
        (__attribute__((address_space(3))) void*)(l), 16, 0, 0);
}

// Involutive byte-swizzle for 128B-row LDS tiles: XOR row bits (7-9) into
// 16B-slot bits (4-6). Measured 0 conflicts (rounds 5-7).
static __device__ __forceinline__ int swz128(int p) {
    return p ^ (((p >> 7) & 7) << 4);
}

// ---------------------------------------------------------------------------
// prep0: [0,256) transpose Wv[d][i] -> Wvt[i][d] bf16 (64x64 tiles, padded
//        fp32 LDS); [256,512) Wlin -> Wlb bf16; [512,768) bias fold.
// ---------------------------------------------------------------------------
__global__ __launch_bounds__(256) void prep0_kernel(
    const float* __restrict__ Wv, const float* __restrict__ Wlin,
    const float* __restrict__ bv, const float* __restrict__ blin,
    unsigned short* __restrict__ Wvt, unsigned short* __restrict__ Wlb,
    float* __restrict__ bcomb) {
    __shared__ float Tl[64 * 65];
    const int bid = blockIdx.x;
    const int t = threadIdx.x;

    if (bid < 256) {
        const int dt = bid >> 4;
        const int it = bid & 15;
        const int r = t >> 2;
        const int c0 = (t & 3) * 16;
        #pragma unroll
        for (int u = 0; u < 4; ++u) {
            float4 v = *(const float4*)&Wv[((size_t)(dt * 64 + r)) * NDIM + it * 64 + c0 + 4 * u];
            Tl[r * 65 + c0 + 4 * u + 0] = v.x;
            Tl[r * 65 + c0 + 4 * u + 1] = v.y;
            Tl[r * 65 + c0 + 4 * u + 2] = v.z;
            Tl[r * 65 + c0 + 4 * u + 3] = v.w;
        }
        __syncthreads();
        const int i = t >> 2;
        const int dq = (t & 3) * 16;
        float v[16];
        #pragma unroll
        for (int u = 0; u < 16; ++u) v[u] = Tl[(dq + u) * 65 + i];
        u16x8 p0 = { f2bf(v[0]), f2bf(v[1]), f2bf(v[2]), f2bf(v[3]),
                     f2bf(v[4]), f2bf(v[5]), f2bf(v[6]), f2bf(v[7]) };
        u16x8 p1 = { f2bf(v[8]), f2bf(v[9]), f2bf(v[10]), f2bf(v[11]),
                     f2bf(v[12]), f2bf(v[13]), f2bf(v[14]), f2bf(v[15]) };
        unsigned short* dst = &Wvt[((size_t)(it * 64 + i)) * KDIM + dt * 64 + dq];
        *(u16x8*)dst = p0;
        *(u16x8*)(dst + 8) = p1;
    } else if (bid < 512) {
        const size_t idx = (((size_t)(bid - 256)) * 256 + t) * 16;
        float4 a = *(const float4*)&Wlin[idx];
        float4 b = *(const float4*)&Wlin[idx + 4];
        float4 c = *(const float4*)&Wlin[idx + 8];
        float4 d = *(const float4*)&Wlin[idx + 12];
        *(u16x8*)&Wlb[idx] = pack8(a, b);
        *(u16x8*)&Wlb[idx + 8] = pack8(c, d);
    } else {
        const int wave = t >> 6, lane = t & 63;
        const int o = (bid - 512) * 4 + wave;
        float s = 0.f;
        for (int d = lane; d < KDIM; d += 64) s += Wlin[o * KDIM + d] * bv[d];
        #pragma unroll
        for (int off = 32; off > 0; off >>= 1) s += __shfl_down(s, off, 64);
        if (lane == 0) bcomb[o] = s + blin[o];
    }
}

// ---------------------------------------------------------------------------
// prep1: [0,256): Wc[o][i] = sum_d Wlb[o][d]*Wvt[i][d] (64x64 tiles, full
//        chip); [256,2304): Xb = bf16(xs). GEMM hides under the conversion.
// ---------------------------------------------------------------------------
__global__ __launch_bounds__(256) void prep1_kernel(
    const unsigned short* __restrict__ Wlb, const unsigned short* __restrict__ Wvt,
    const float* __restrict__ xs, unsigned short* __restrict__ Wc,
    unsigned short* __restrict__ Xb) {
    __shared__ unsigned short As[64 * 32];
    __shared__ unsigned short Bs[64 * 32];
    const int bid = blockIdx.x;
    const int t = threadIdx.x;

    if (bid >= 256) {
        // ---- xs -> bf16 ----
        const size_t base = (((size_t)(bid - 256)) * 256 + t) * 8;
        #pragma unroll
        for (int itr = 0; itr < 4; ++itr) {
            const size_t idx = base + (size_t)itr * (size_t)(2048 * 256 * 8);
            float4 a = *(const float4*)&xs[idx];
            float4 b = *(const float4*)&xs[idx + 4];
            *(u16x8*)&Xb[idx] = pack8(a, b);
        }
        return;
    }

    // ---- wcomb 64x64 tile ----
    const int ot = bid >> 4;
    const int it = bid & 15;
    const int w = t >> 6, l = t & 63;
    const int wr = (w >> 1) * 32, wc = (w & 1) * 32;
    const int lr = l & 15, lk = l >> 4;

    f32x4 acc[2][2] = {};

    const unsigned short* gA = &Wlb[((size_t)(ot * 64 + (t >> 2))) * KDIM + (t & 3) * 8];
    const unsigned short* gB = &Wvt[((size_t)(it * 64 + (t >> 2))) * KDIM + (t & 3) * 8];
    unsigned short* lA = &As[w * 512];
    unsigned short* lB = &Bs[w * 512];

    for (int kt = 0; kt < KDIM / 32; ++kt) {
        gload16(gA + kt * 32, lA);
        gload16(gB + kt * 32, lB);
        __syncthreads();
        bf16x8 af[2], bfr[2];
        #pragma unroll
        for (int fi = 0; fi < 2; ++fi)
            af[fi] = *(bf16x8*)&As[(wr + fi * 16 + lr) * 32 + lk * 8];
        #pragma unroll
        for (int fj = 0; fj < 2; ++fj)
            bfr[fj] = *(bf16x8*)&Bs[(wc + fj * 16 + lr) * 32 + lk * 8];
        #pragma unroll
        for (int fi = 0; fi < 2; ++fi)
            #pragma unroll
            for (int fj = 0; fj < 2; ++fj)
                acc[fi][fj] = __builtin_amdgcn_mfma_f32_16x16x32_bf16(
                    af[fi], bfr[fj], acc[fi][fj], 0, 0, 0);
        __syncthreads();
    }
    #pragma unroll
    for (int fi = 0; fi < 2; ++fi)
        #pragma unroll
        for (int fj = 0; fj < 2; ++fj)
            #pragma unroll
            for (int r = 0; r < 4; ++r) {
                const int o = ot * 64 + wr + fi * 16 + lk * 4 + r;
                const int i = it * 64 + wc + fj * 16 + lr;
                Wc[(size_t)o * KDIM + i] = f2bf(acc[fi][fj][r]);
            }
}

// ---------------------------------------------------------------------------
// main_ring: out = leaky(Xb @ Wc^T + bcomb). Round-4 schedule, new geometry.
// BM=BN=256, BK=32, 8 waves (2Mx4N), per-wave 128x64 = acc[8][4].
// 4-buffer LDS ring (4 x 32KB), prefetch 3 tiles, counted vmcnt(8)/tile,
// 2 phases/tile, setprio, plain barriers.
// LDS tile layout (per operand, 16KB): bf16 [256][32] packed as row-pairs:
//   P(r,k) = (r>>1)*128 + (r&1)*64 + k*2, physical = swz128(P).
// Staging: linear gload_lds dest q; source pre-swizzled (p = swz128(q)).
// Grid 256 = 1 block/CU, bijective XCD swizzle.
// ---------------------------------------------------------------------------
__global__ __launch_bounds__(512, 2) void main_ring(
    const unsigned short* __restrict__ Xb, const unsigned short* __restrict__ Wc,
    const float* __restrict__ bcomb, float* __restrict__ out) {
    extern __shared__ char lds[];  // 131072
    const int tid = threadIdx.x;
    const int w = tid >> 6, l = tid & 63;
    const int wm = w >> 2, wn = w & 3;
    const int lr = l & 15, lk = l >> 4;

    // XCD swizzle (256 % 8 == 0, bijective)
    const int swzb = ((blockIdx.x & 7) << 5) + (blockIdx.x >> 3);
    const int mt = swzb >> 2, nt = swzb & 3;

    // reader LDS byte offsets within one 32KB buffer
    int aoff[8], boff[4];
    #pragma unroll
    for (int fi = 0; fi < 8; ++fi) {
        const int r = wm * 128 + fi * 16 + lr;
        aoff[fi] = swz128(((r >> 1) << 7) | ((r & 1) << 6) | (lk << 4));
    }
    #pragma unroll
    for (int fj = 0; fj < 4; ++fj) {
        const int r = wn * 64 + fj * 16 + lr;
        boff[fj] = 16384 + swz128(((r >> 1) << 7) | ((r & 1) << 6) | (lk << 4));
    }

    // staging: per-lane pre-swizzled global sources, linear LDS dests.
    const char* srcA0; const char* srcA1; const char* srcB0; const char* srcB1;
    {
        const int q0 = 0 * 8192 + w * 1024 + l * 16, p0 = swz128(q0);
        const int q1 = 1 * 8192 + w * 1024 + l * 16, p1 = swz128(q1);
        const int r0 = ((p0 >> 7) << 1) | ((p0 >> 6) & 1), c0 = p0 & 63;
        const int r1 = ((p1 >> 7) << 1) | ((p1 >> 6) & 1), c1 = p1 & 63;
        srcA0 = (const char*)Xb + ((size_t)(mt * 256 + r0) * KDIM) * 2 + c0;
        srcA1 = (const char*)Xb + ((size_t)(mt * 256 + r1) * KDIM) * 2 + c1;
        srcB0 = (const char*)Wc + ((size_t)(nt * 256 + r0) * KDIM) * 2 + c0;
        srcB1 = (const char*)Wc + ((size_t)(nt * 256 + r1) * KDIM) * 2 + c1;
    }
    const int ldsw = w * 1024;

    f32x4 acc[8][4] = {};

    // prologue: stage K-tiles 0,1,2 into buffers 0,1,2 (4 loads each)
    #pragma unroll
    for (int pt = 0; pt < 3; ++pt) {
        char* bb = lds + pt * 32768;
        gload16(srcA0 + (size_t)pt * 64, bb + ldsw);
        gload16(srcA1 + (size_t)pt * 64, bb + 8192 + ldsw);
        gload16(srcB0 + (size_t)pt * 64, bb + 16384 + ldsw);
        gload16(srcB1 + (size_t)pt * 64, bb + 24576 + ldsw);
    }

#define KTILE(T, STAGE_EN)                                                     \
    do {                                                                       \
        const char* bufp = lds + (size_t)((T) & 3) * 32768;                    \
        char* nb = lds + (size_t)(((T) + 3) & 3) * 32768;                      \
        /* phase A: stage A-chunks of T+3; read B frags + low A frags */       \
        if (STAGE_EN) {                                                        \
            gload16(srcA0 + (size_t)((T) + 3) * 64, nb + ldsw);                \
            gload16(srcA1 + (size_t)((T) + 3) * 64, nb + 8192 + ldsw);         \
        }                                                                      \
        bf16x8 bfr[4], afr[4];                                                 \
        _Pragma("unroll")                                                      \
        for (int fj = 0; fj < 4; ++fj)                                         \
            bfr[fj] = *(const bf16x8*)(bufp + boff[fj]);                       \
        _Pragma("unroll")                                                      \
        for (int fi = 0; fi < 4; ++fi)                                         \
            afr[fi] = *(const bf16x8*)(bufp + aoff[fi]);                       \
        __builtin_amdgcn_s_barrier();                                          \
        __builtin_amdgcn_s_setprio(1);                                         \
        _Pragma("unroll")                                                      \
        for (int fi = 0; fi < 4; ++fi)                                         \
            _Pragma("unroll")                                                  \
            for (int fj = 0; fj < 4; ++fj)                                     \
                acc[fi][fj] = __builtin_amdgcn_mfma_f32_16x16x32_bf16(         \
                    afr[fi], bfr[fj], acc[fi][fj], 0, 0, 0);                   \
        __builtin_amdgcn_s_setprio(0);                                         \
        __builtin_amdgcn_s_barrier();                                          \
        /* phase B: stage B-chunks of T+3; read high A frags */                \
        if (STAGE_EN) {                                                        \
            gload16(srcB0 + (size_t)((T) + 3) * 64, nb + 16384 + ldsw);        \
            gload16(srcB1 + (size_t)((T) + 3) * 64, nb + 24576 + ldsw);        \
        }                                                                      \
        bf16x8 af2[4];                                                         \
        _Pragma("unroll")                                                      \
        for (int fi = 0; fi < 4; ++fi)                                         \
            af2[fi] = *(const bf16x8*)(bufp + aoff[4 + fi]);                   \
        __builtin_amdgcn_s_barrier();                                          \
        __builtin_amdgcn_s_setprio(1);                                         \
        _Pragma("unroll")                                                      \
        for (int fi = 0; fi < 4; ++fi)                                         \
            _Pragma("unroll")                                                  \
            for (int fj = 0; fj < 4; ++fj)                                     \
                acc[4 + fi][fj] = __builtin_amdgcn_mfma_f32_16x16x32_bf16(     \
                    af2[fi], bfr[fj], acc[4 + fi][fj], 0, 0, 0);               \
        __builtin_amdgcn_s_setprio(0);                                         \
    } while (0)

    // main loop: K-tiles 0..28, staging tile t+3 (3..31)
    for (int t = 0; t < NT - 3; ++t) {
        asm volatile("s_waitcnt vmcnt(8)" ::: "memory");  // buf[t] resident
        __builtin_amdgcn_s_barrier();
        KTILE(t, 1);
    }
    // tail: 29, 30, 31 (no staging; decreasing counted waits)
    asm volatile("s_waitcnt vmcnt(8)" ::: "memory");
    __builtin_amdgcn_s_barrier();
    KTILE(29, 0);
    asm volatile("s_waitcnt vmcnt(4)" ::: "memory");
    __builtin_amdgcn_s_barrier();
    KTILE(30, 0);
    asm volatile("s_waitcnt vmcnt(0)" ::: "memory");
    __builtin_amdgcn_s_barrier();
    KTILE(31, 0);
#undef KTILE

    // epilogue: + bias, leaky_relu, fp32 store
    #pragma unroll
    for (int fi = 0; fi < 8; ++fi)
        #pragma unroll
        for (int fj = 0; fj < 4; ++fj) {
            const int col = nt * 256 + wn * 64 + fj * 16 + lr;
            const float b = bcomb[col];
            #pragma unroll
            for (int r = 0; r < 4; ++r) {
                const int row = mt * 256 + wm * 128 + fi * 16 + lk * 4 + r;
                float v = acc[fi][fj][r] + b;
                out[(size_t)row * NDIM + col] = v >= 0.f ? v : 0.01f * v;
            }
        }
}

// ---------------------------------------------------------------------------
// Fallback main GEMM (fused fp32->bf16 A path, 128x128) if ws is too small.
// ---------------------------------------------------------------------------
__global__ __launch_bounds__(256) void main_gemm_f32(
    const float* __restrict__ X, const unsigned short* __restrict__ Wc,
    const float* __restrict__ bcomb, float* __restrict__ out) {
    __shared__ unsigned short As[128 * 32];
    __shared__ unsigned short Bs[128 * 32];
    const int t = threadIdx.x;
    const int nt = blockIdx.x & 7;
    const int mt = blockIdx.x >> 3;
    const int w = t >> 6, l = t & 63;
    const int wr = (w >> 1) * 64, wcc = (w & 1) * 64;
    const int lr = l & 15, lk = l >> 4;

    f32x4 acc[4][4] = {};

    const int arow = t >> 3;
    const int akq = t & 7;
    const int brow = t >> 2;
    const int bc4 = t & 3;

    for (int kt = 0; kt < KDIM / 32; ++kt) {
        float4 av[4];
        #pragma unroll
        for (int j = 0; j < 4; ++j) {
            const int row = j * 32 + arow;
            av[j] = *(const float4*)&X[(mt * 128 + row) * KDIM + kt * 32 + akq * 4];
        }
        __syncthreads();
        #pragma unroll
        for (int j = 0; j < 4; ++j) {
            const int row = j * 32 + arow;
            u16x4 p = { f2bf(av[j].x), f2bf(av[j].y), f2bf(av[j].z), f2bf(av[j].w) };
            *(u16x4*)&As[row * 32 + akq * 4] = p;
        }
        #pragma unroll
        for (int j = 0; j < 2; ++j) {
            const int row = j * 64 + brow;
            const unsigned short* g = &Wc[(nt * 128 + row) * KDIM + kt * 32 + bc4 * 8];
            unsigned short* ldst = &Bs[(j * 256 + w * 64) * 8];
            gload16(g, ldst);
        }
        __syncthreads();
        bf16x8 af[4], bfr[4];
        #pragma unroll
        for (int fi = 0; fi < 4; ++fi)
            af[fi] = *(bf16x8*)&As[(wr + fi * 16 + lr) * 32 + lk * 8];
        #pragma unroll
        for (int fj = 0; fj < 4; ++fj)
            bfr[fj] = *(bf16x8*)&Bs[(wcc + fj * 16 + lr) * 32 + lk * 8];
        #pragma unroll
        for (int fi = 0; fi < 4; ++fi)
            #pragma unroll
            for (int fj = 0; fj < 4; ++fj)
                acc[fi][fj] = __builtin_amdgcn_mfma_f32_16x16x32_bf16(
                    af[fi], bfr[fj], acc[fi][fj], 0, 0, 0);
    }

    #pragma unroll
    for (int fi = 0; fi < 4; ++fi)
        #pragma unroll
        for (int fj = 0; fj < 4; ++fj) {
            const int col = nt * 128 + wcc + fj * 16 + lr;
            const float b = bcomb[col];
            #pragma unroll
            for (int r = 0; r < 4; ++r) {
                const int row = mt * 128 + wr + fi * 16 + lk * 4 + r;
                float v = acc[fi][fj][r] + b;
                out[row * NDIM + col] = v >= 0.f ? v : 0.01f * v;
            }
        }
}

extern "C" void kernel_launch(void* const* d_in, const int* in_sizes, int n_in,
                              void* d_out, int out_size, void* d_ws, size_t ws_size,
                              hipStream_t stream) {
    const float* xs   = (const float*)d_in[0];
    // d_in[1] mask unused: softmax row-sums are exactly 1.
    const float* Wv   = (const float*)d_in[6];
    const float* bv   = (const float*)d_in[7];
    const float* Wlin = (const float*)d_in[8];
    const float* blin = (const float*)d_in[9];

    unsigned short* Wc = (unsigned short*)d_ws;                         // 2 MB
    float* bcomb = (float*)((char*)d_ws + 2097152);                     // 4 KB
    unsigned short* Xb = (unsigned short*)((char*)d_ws + 2101248);      // 32 MB
    float* out = (float*)d_out;

    // transient scratch in d_out (64 MB, fully overwritten by the final GEMM)
    unsigned short* Wvt = (unsigned short*)d_out;                       // 2 MB
    unsigned short* Wlb = (unsigned short*)((char*)d_out + 2097152);    // 2 MB

    const size_t NEED = 2101248 + (size_t)M_TOT * KDIM * 2;
    hipLaunchKernelGGL(prep0_kernel, dim3(768), dim3(256), 0, stream,
                       Wv, Wlin, bv, blin, Wvt, Wlb, bcomb);
    if (ws_size >= NEED) {
        (void)hipFuncSetAttribute((const void*)main_ring,
                                  hipFuncAttributeMaxDynamicSharedMemorySize,
                                  131072);
        hipLaunchKernelGGL(prep1_kernel, dim3(256 + 2048), dim3(256), 0, stream,
                           Wlb, Wvt, xs, Wc, Xb);
        hipLaunchKernelGGL(main_ring, dim3(256), dim3(512), 131072, stream,
                           Xb, Wc, bcomb, out);
    } else {
        hipLaunchKernelGGL(prep1_kernel, dim3(256), dim3(256), 0, stream,
                           Wlb, Wvt, xs, Wc, Xb);
        hipLaunchKernelGGL(main_gemm_f32, dim3((M_TOT / 128) * (NDIM / 128)),
                           dim3(256), 0, stream, xs, Wc, bcomb, out);
    }
}

// Round 11
// 74.132 us; speedup vs baseline: 1.3304x; 1.0106x over previous
//
#include <hip/hip_runtime.h>
#include <hip/hip_bf16.h>
#include <stdint.h>

// Problem: B=16, S=1024, IN=1024, OUT=1024.
// Reference collapses: softmax row-sums are exactly 1 (key mask always has >=1
// live column), so out = leaky_relu(xs @ (Wlin@Wv)^T + (Wlin@bv + blin)).
//
// Round 11: main GEMM ported to the m201-style 4-phase BK=64 double-buffered
// schedule: per K-tile 4 phases of {ds_read subtile -> gload issue -> barrier
// -> lgkmcnt(0) -> setprio(1) -> 16 MFMA -> setprio(0) -> barrier}; A(T+1)
// issued at P0, B(T+2) at P3 (into current buf's B region, free after P2);
// counted vmcnt(4) at tile boundary. BK=64 gives native 128B rows = the
// zero-conflict swz128 geometry measured in rounds 5-7/10.

#define M_TOT 16384   // B*S
#define KDIM  1024
#define NDIM  1024
#define NKT   16      // K-tiles of BK=64 in main GEMM

typedef __attribute__((ext_vector_type(8))) short bf16x8;
typedef __attribute__((ext_vector_type(4))) float f32x4;
typedef __attribute__((ext_vector_type(4))) unsigned short u16x4;
typedef __attribute__((ext_vector_type(8))) unsigned short u16x8;

static __device__ __forceinline__ unsigned short f2bf(float f) {
    union { float f; unsigned int u; } v; v.f = f;
    unsigned int u = v.u;
    return (unsigned short)((u + 0x7fffu + ((u >> 16) & 1u)) >> 16);  // RNE
}

static __device__ __forceinline__ u16x8 pack8(float4 a, float4 b) {
    u16x8 p = { f2bf(a.x), f2bf(a.y), f2bf(a.z), f2bf(a.w),
                f2bf(b.x), f2bf(b.y), f2bf(b.z), f2bf(b.w) };
    return p;
}

static __device__ __forceinline__ void gload16(const void* g, void* l) {
    __builtin_amdgcn_global_load_lds(
        (__attribute__((address_space(1))) void*)(g),
        (__attribute__((address_space(3))) void*)(l), 16, 0, 0);
}

// Involutive byte-swizzle for 128B-row LDS tiles: XOR row bits (7-9) into
// 16B-slot bits (4-6). Measured 0 conflicts (rounds 5-7, 10).
static __device__ __forceinline__ int swz128(int p) {
    return p ^ (((p >> 7) & 7) << 4);
}

// ---------------------------------------------------------------------------
// prep0: [0,256) transpose Wv[d][i] -> Wvt[i][d] bf16 (64x64 tiles, padded
//        fp32 LDS); [256,512) Wlin -> Wlb bf16; [512,768) bias fold.
// ---------------------------------------------------------------------------
__global__ __launch_bounds__(256) void prep0_kernel(
    const float* __restrict__ Wv, const float* __restrict__ Wlin,
    const float* __restrict__ bv, const float* __restrict__ blin,
    unsigned short* __restrict__ Wvt, unsigned short* __restrict__ Wlb,
    float* __restrict__ bcomb) {
    __shared__ float Tl[64 * 65];
    const int bid = blockIdx.x;
    const int t = threadIdx.x;

    if (bid < 256) {
        const int dt = bid >> 4;
        const int it = bid & 15;
        const int r = t >> 2;
        const int c0 = (t & 3) * 16;
        #pragma unroll
        for (int u = 0; u < 4; ++u) {
            float4 v = *(const float4*)&Wv[((size_t)(dt * 64 + r)) * NDIM + it * 64 + c0 + 4 * u];
            Tl[r * 65 + c0 + 4 * u + 0] = v.x;
            Tl[r * 65 + c0 + 4 * u + 1] = v.y;
            Tl[r * 65 + c0 + 4 * u + 2] = v.z;
            Tl[r * 65 + c0 + 4 * u + 3] = v.w;
        }
        __syncthreads();
        const int i = t >> 2;
        const int dq = (t & 3) * 16;
        float v[16];
        #pragma unroll
        for (int u = 0; u < 16; ++u) v[u] = Tl[(dq + u) * 65 + i];
        u16x8 p0 = { f2bf(v[0]), f2bf(v[1]), f2bf(v[2]), f2bf(v[3]),
                     f2bf(v[4]), f2bf(v[5]), f2bf(v[6]), f2bf(v[7]) };
        u16x8 p1 = { f2bf(v[8]), f2bf(v[9]), f2bf(v[10]), f2bf(v[11]),
                     f2bf(v[12]), f2bf(v[13]), f2bf(v[14]), f2bf(v[15]) };
        unsigned short* dst = &Wvt[((size_t)(it * 64 + i)) * KDIM + dt * 64 + dq];
        *(u16x8*)dst = p0;
        *(u16x8*)(dst + 8) = p1;
    } else if (bid < 512) {
        const size_t idx = (((size_t)(bid - 256)) * 256 + t) * 16;
        float4 a = *(const float4*)&Wlin[idx];
        float4 b = *(const float4*)&Wlin[idx + 4];
        float4 c = *(const float4*)&Wlin[idx + 8];
        float4 d = *(const float4*)&Wlin[idx + 12];
        *(u16x8*)&Wlb[idx] = pack8(a, b);
        *(u16x8*)&Wlb[idx + 8] = pack8(c, d);
    } else {
        const int wave = t >> 6, lane = t & 63;
        const int o = (bid - 512) * 4 + wave;
        float s = 0.f;
        for (int d = lane; d < KDIM; d += 64) s += Wlin[o * KDIM + d] * bv[d];
        #pragma unroll
        for (int off = 32; off > 0; off >>= 1) s += __shfl_down(s, off, 64);
        if (lane == 0) bcomb[o] = s + blin[o];
    }
}

// ---------------------------------------------------------------------------
// prep1: [0,256): Wc[o][i] = sum_d Wlb[o][d]*Wvt[i][d] (64x64 tiles);
//        [256,2304): Xb = bf16(xs). GEMM hides under the conversion.
// ---------------------------------------------------------------------------
__global__ __launch_bounds__(256) void prep1_kernel(
    const unsigned short* __restrict__ Wlb, const unsigned short* __restrict__ Wvt,
    const float* __restrict__ xs, unsigned short* __restrict__ Wc,
    unsigned short* __restrict__ Xb) {
    __shared__ unsigned short As[64 * 32];
    __shared__ unsigned short Bs[64 * 32];
    const int bid = blockIdx.x;
    const int t = threadIdx.x;

    if (bid >= 256) {
        const size_t base = (((size_t)(bid - 256)) * 256 + t) * 8;
        #pragma unroll
        for (int itr = 0; itr < 4; ++itr) {
            const size_t idx = base + (size_t)itr * (size_t)(2048 * 256 * 8);
            float4 a = *(const float4*)&xs[idx];
            float4 b = *(const float4*)&xs[idx + 4];
            *(u16x8*)&Xb[idx] = pack8(a, b);
        }
        return;
    }

    const int ot = bid >> 4;
    const int it = bid & 15;
    const int w = t >> 6, l = t & 63;
    const int wr = (w >> 1) * 32, wc = (w & 1) * 32;
    const int lr = l & 15, lk = l >> 4;

    f32x4 acc[2][2] = {};

    const unsigned short* gA = &Wlb[((size_t)(ot * 64 + (t >> 2))) * KDIM + (t & 3) * 8];
    const unsigned short* gB = &Wvt[((size_t)(it * 64 + (t >> 2))) * KDIM + (t & 3) * 8];
    unsigned short* lA = &As[w * 512];
    unsigned short* lB = &Bs[w * 512];

    for (int kt = 0; kt < KDIM / 32; ++kt) {
        gload16(gA + kt * 32, lA);
        gload16(gB + kt * 32, lB);
        __syncthreads();
        bf16x8 af[2], bfr[2];
        #pragma unroll
        for (int fi = 0; fi < 2; ++fi)
            af[fi] = *(bf16x8*)&As[(wr + fi * 16 + lr) * 32 + lk * 8];
        #pragma unroll
        for (int fj = 0; fj < 2; ++fj)
            bfr[fj] = *(bf16x8*)&Bs[(wc + fj * 16 + lr) * 32 + lk * 8];
        #pragma unroll
        for (int fi = 0; fi < 2; ++fi)
            #pragma unroll
            for (int fj = 0; fj < 2; ++fj)
                acc[fi][fj] = __builtin_amdgcn_mfma_f32_16x16x32_bf16(
                    af[fi], bfr[fj], acc[fi][fj], 0, 0, 0);
        __syncthreads();
    }
    #pragma unroll
    for (int fi = 0; fi < 2; ++fi)
        #pragma unroll
        for (int fj = 0; fj < 2; ++fj)
            #pragma unroll
            for (int r = 0; r < 4; ++r) {
                const int o = ot * 64 + wr + fi * 16 + lk * 4 + r;
                const int i = it * 64 + wc + fj * 16 + lr;
                Wc[(size_t)o * KDIM + i] = f2bf(acc[fi][fj][r]);
            }
}

// ---------------------------------------------------------------------------
// main_8p: out = leaky(Xb @ Wc^T + bcomb). m201-style 4-phase BK=64 schedule.
// BM=BN=256, BK=64, 8 waves (2Mx4N), per-wave 128x64 = acc[8][4].
// LDS 131072 = 2 bufs x (A 32KB [256][64]bf16 swz128 @0, B 32KB @32768).
// Staging: linear gload_lds dest, pre-swizzled per-lane source (rule #21).
//   tile T: A(T+1) issued at P0 (-> other buf, A region free since T-1 P3);
//           B(T+2) issued at P3 (-> current buf B region, free after P2).
// Boundary: counted vmcnt(4) (= B(T+2) in flight), never 0 until tail.
// Grid 256 = 1 block/CU, bijective XCD swizzle.
// ---------------------------------------------------------------------------
__global__ __launch_bounds__(512, 2) void main_8p(
    const unsigned short* __restrict__ Xb, const unsigned short* __restrict__ Wc,
    const float* __restrict__ bcomb, float* __restrict__ out) {
    extern __shared__ char lds[];  // 131072
    const int tid = threadIdx.x;
    const int w = tid >> 6, l = tid & 63;
    const int wm = w >> 2, wn = w & 3;
    const int lr = l & 15, lk = l >> 4;

    // XCD swizzle (256 % 8 == 0, bijective)
    const int swzb = ((blockIdx.x & 7) << 5) + (blockIdx.x >> 3);
    const int mt = swzb >> 2, nt = swzb & 3;

    // reader LDS byte offsets (kk=0); kk=1 is ^64 (swz128 commutes with ^64)
    int aoff[8], boff[4];
    #pragma unroll
    for (int fi = 0; fi < 8; ++fi)
        aoff[fi] = swz128((wm * 128 + fi * 16 + lr) * 128 + lk * 16);
    #pragma unroll
    for (int fj = 0; fj < 4; ++fj)
        boff[fj] = 32768 + swz128((wn * 64 + fj * 16 + lr) * 128 + lk * 16);

    // staging: per-lane pre-swizzled global sources, linear LDS dests.
    const char* srcA[4];
    const char* srcB[4];
    #pragma unroll
    for (int j = 0; j < 4; ++j) {
        const int q = j * 8192 + w * 1024 + l * 16;
        const int p = swz128(q);
        const int r = p >> 7, c = p & 127;
        srcA[j] = (const char*)Xb + ((size_t)(mt * 256 + r) * KDIM) * 2 + c;
        srcB[j] = (const char*)Wc + ((size_t)(nt * 256 + r) * KDIM) * 2 + c;
    }
    const int ldsw = w * 1024;

    f32x4 acc[8][4] = {};

#define GLOAD_A(T, BUF)                                                        \
    do {                                                                       \
        gload16(srcA[0] + (size_t)(T) * 128, (BUF) + 0 * 8192 + ldsw);         \
        gload16(srcA[1] + (size_t)(T) * 128, (BUF) + 1 * 8192 + ldsw);         \
        gload16(srcA[2] + (size_t)(T) * 128, (BUF) + 2 * 8192 + ldsw);         \
        gload16(srcA[3] + (size_t)(T) * 128, (BUF) + 3 * 8192 + ldsw);         \
    } while (0)
#define GLOAD_B(T, BUF)                                                        \
    do {                                                                       \
        gload16(srcB[0] + (size_t)(T) * 128, (BUF) + 32768 + 0 * 8192 + ldsw); \
        gload16(srcB[1] + (size_t)(T) * 128, (BUF) + 32768 + 1 * 8192 + ldsw); \
        gload16(srcB[2] + (size_t)(T) * 128, (BUF) + 32768 + 2 * 8192 + ldsw); \
        gload16(srcB[3] + (size_t)(T) * 128, (BUF) + 32768 + 3 * 8192 + ldsw); \
    } while (0)

    // prologue: A(0),B(0) -> buf0; B(1) -> buf1; wait A0/B0 (B1 in flight)
    GLOAD_A(0, lds);
    GLOAD_B(0, lds);
    GLOAD_B(1, lds + 65536);
    asm volatile("s_waitcnt vmcnt(4)" ::: "memory");
    __builtin_amdgcn_s_barrier();

#define MFMA16(ACCI, AF, BF)                                                   \
    _Pragma("unroll")                                                          \
    for (int fi = 0; fi < 4; ++fi)                                             \
        _Pragma("unroll")                                                      \
        for (int fj = 0; fj < 4; ++fj)                                         \
            acc[(ACCI) + fi][fj] = __builtin_amdgcn_mfma_f32_16x16x32_bf16(    \
                (AF)[fi], (BF)[fj], acc[(ACCI) + fi][fj], 0, 0, 0)

#define LGKM0() asm volatile("s_waitcnt lgkmcnt(0)" ::: "memory")

    // KTILE T: compute from buf[T&1]; SA: issue A(T+1) at P0; SB: issue
    // B(T+2) at P3 (into buf[T&1] B region); WN: boundary counted vmcnt.
#define KTILE(T, SA, SB, WN)                                                   \
    do {                                                                       \
        const char* cbuf = lds + (((T) & 1) << 16);                            \
        char* nbuf = lds + ((((T) & 1) ^ 1) << 16);                            \
        char* cbw = lds + (((T) & 1) << 16);                                   \
        /* P0: read B kk0 + A fi0-3 kk0; issue A(T+1) */                       \
        bf16x8 b0[4], a0[4];                                                   \
        _Pragma("unroll")                                                      \
        for (int fj = 0; fj < 4; ++fj)                                         \
            b0[fj] = *(const bf16x8*)(cbuf + boff[fj]);                        \
        _Pragma("unroll")                                                      \
        for (int fi = 0; fi < 4; ++fi)                                         \
            a0[fi] = *(const bf16x8*)(cbuf + aoff[fi]);                        \
        if (SA) { GLOAD_A((T) + 1, nbuf); }                                    \
        __builtin_amdgcn_s_barrier();                                          \
        LGKM0();                                                               \
        __builtin_amdgcn_s_setprio(1);                                         \
        MFMA16(0, a0, b0);                                                     \
        __builtin_amdgcn_s_setprio(0);                                         \
        __builtin_amdgcn_s_barrier();                                          \
        /* P1: read A fi4-7 kk0 */                                             \
        bf16x8 a1[4];                                                          \
        _Pragma("unroll")                                                      \
        for (int fi = 0; fi < 4; ++fi)                                         \
            a1[fi] = *(const bf16x8*)(cbuf + aoff[4 + fi]);                    \
        __builtin_amdgcn_s_barrier();                                          \
        LGKM0();                                                               \
        __builtin_amdgcn_s_setprio(1);                                         \
        MFMA16(4, a1, b0);                                                     \
        __builtin_amdgcn_s_setprio(0);                                         \
        __builtin_amdgcn_s_barrier();                                          \
        /* P2: read B kk1 + A fi0-3 kk1 */                                     \
        bf16x8 b1[4], a2[4];                                                   \
        _Pragma("unroll")                                                      \
        for (int fj = 0; fj < 4; ++fj)                                         \
            b1[fj] = *(const bf16x8*)(cbuf + (boff[fj] ^ 64));                 \
        _Pragma("unroll")                                                      \
        for (int fi = 0; fi < 4; ++fi)                                         \
            a2[fi] = *(const bf16x8*)(cbuf + (aoff[fi] ^ 64));                 \
        __builtin_amdgcn_s_barrier();                                          \
        LGKM0();                                                               \
        __builtin_amdgcn_s_setprio(1);                                         \
        MFMA16(0, a2, b1);                                                     \
        __builtin_amdgcn_s_setprio(0);                                         \
        __builtin_amdgcn_s_barrier();                                          \
        /* P3: read A fi4-7 kk1; issue B(T+2) into current buf (free now) */   \
        bf16x8 a3[4];                                                          \
        _Pragma("unroll")                                                      \
        for (int fi = 0; fi < 4; ++fi)                                         \
            a3[fi] = *(const bf16x8*)(cbuf + (aoff[4 + fi] ^ 64));             \
        if (SB) { GLOAD_B((T) + 2, cbw); }                                     \
        __builtin_amdgcn_s_barrier();                                          \
        LGKM0();                                                               \
        __builtin_amdgcn_s_setprio(1);                                         \
        MFMA16(4, a3, b1);                                                     \
        __builtin_amdgcn_s_setprio(0);                                         \
        /* boundary: next tile resident at counted vmcnt */                    \
        asm volatile("s_waitcnt vmcnt(" #WN ")" ::: "memory");                 \
        __builtin_amdgcn_s_barrier();                                          \
    } while (0)

    // steady: T=0..13 (A up to 14, B up to 15); tail T=14 (A15, no B), T=15
    for (int t = 0; t < NKT - 2; ++t) {
        KTILE(t, 1, 1, 4);
    }
    KTILE(14, 1, 0, 0);
    KTILE(15, 0, 0, 0);
#undef KTILE
#undef LGKM0
#undef MFMA16
#undef GLOAD_B
#undef GLOAD_A

    // epilogue: + bias, leaky_relu, fp32 store
    #pragma unroll
    for (int fi = 0; fi < 8; ++fi)
        #pragma unroll
        for (int fj = 0; fj < 4; ++fj) {
            const int col = nt * 256 + wn * 64 + fj * 16 + lr;
            const float b = bcomb[col];
            #pragma unroll
            for (int r = 0; r < 4; ++r) {
                const int row = mt * 256 + wm * 128 + fi * 16 + lk * 4 + r;
                float v = acc[fi][fj][r] + b;
                out[(size_t)row * NDIM + col] = v >= 0.f ? v : 0.01f * v;
            }
        }
}

// ---------------------------------------------------------------------------
// Fallback main GEMM (fused fp32->bf16 A path, 128x128) if ws is too small.
// ---------------------------------------------------------------------------
__global__ __launch_bounds__(256) void main_gemm_f32(
    const float* __restrict__ X, const unsigned short* __restrict__ Wc,
    const float* __restrict__ bcomb, float* __restrict__ out) {
    __shared__ unsigned short As[128 * 32];
    __shared__ unsigned short Bs[128 * 32];
    const int t = threadIdx.x;
    const int nt = blockIdx.x & 7;
    const int mt = blockIdx.x >> 3;
    const int w = t >> 6, l = t & 63;
    const int wr = (w >> 1) * 64, wcc = (w & 1) * 64;
    const int lr = l & 15, lk = l >> 4;

    f32x4 acc[4][4] = {};

    const int arow = t >> 3;
    const int akq = t & 7;
    const int brow = t >> 2;
    const int bc4 = t & 3;

    for (int kt = 0; kt < KDIM / 32; ++kt) {
        float4 av[4];
        #pragma unroll
        for (int j = 0; j < 4; ++j) {
            const int row = j * 32 + arow;
            av[j] = *(const float4*)&X[(mt * 128 + row) * KDIM + kt * 32 + akq * 4];
        }
        __syncthreads();
        #pragma unroll
        for (int j = 0; j < 4; ++j) {
            const int row = j * 32 + arow;
            u16x4 p = { f2bf(av[j].x), f2bf(av[j].y), f2bf(av[j].z), f2bf(av[j].w) };
            *(u16x4*)&As[row * 32 + akq * 4] = p;
        }
        #pragma unroll
        for (int j = 0; j < 2; ++j) {
            const int row = j * 64 + brow;
            const unsigned short* g = &Wc[(nt * 128 + row) * KDIM + kt * 32 + bc4 * 8];
            unsigned short* ldst = &Bs[(j * 256 + w * 64) * 8];
            gload16(g, ldst);
        }
        __syncthreads();
        bf16x8 af[4], bfr[4];
        #pragma unroll
        for (int fi = 0; fi < 4; ++fi)
            af[fi] = *(bf16x8*)&As[(wr + fi * 16 + lr) * 32 + lk * 8];
        #pragma unroll
        for (int fj = 0; fj < 4; ++fj)
            bfr[fj] = *(bf16x8*)&Bs[(wcc + fj * 16 + lr) * 32 + lk * 8];
        #pragma unroll
        for (int fi = 0; fi < 4; ++fi)
            #pragma unroll
            for (int fj = 0; fj < 4; ++fj)
                acc[fi][fj] = __builtin_amdgcn_mfma_f32_16x16x32_bf16(
                    af[fi], bfr[fj], acc[fi][fj], 0, 0, 0);
    }

    #pragma unroll
    for (int fi = 0; fi < 4; ++fi)
        #pragma unroll
        for (int fj = 0; fj < 4; ++fj) {
            const int col = nt * 128 + wcc + fj * 16 + lr;
            const float b = bcomb[col];
            #pragma unroll
            for (int r = 0; r < 4; ++r) {
                const int row = mt * 128 + wr + fi * 16 + lk * 4 + r;
                float v = acc[fi][fj][r] + b;
                out[row * NDIM + col] = v >= 0.f ? v : 0.01f * v;
            }
        }
}

extern "C" void kernel_launch(void* const* d_in, const int* in_sizes, int n_in,
                              void* d_out, int out_size, void* d_ws, size_t ws_size,
                              hipStream_t stream) {
    const float* xs   = (const float*)d_in[0];
    // d_in[1] mask unused: softmax row-sums are exactly 1.
    const float* Wv   = (const float*)d_in[6];
    const float* bv   = (const float*)d_in[7];
    const float* Wlin = (const float*)d_in[8];
    const float* blin = (const float*)d_in[9];

    unsigned short* Wc = (unsigned short*)d_ws;                         // 2 MB
    float* bcomb = (float*)((char*)d_ws + 2097152);                     // 4 KB
    unsigned short* Xb = (unsigned short*)((char*)d_ws + 2101248);      // 32 MB
    float* out = (float*)d_out;

    // transient scratch in d_out (64 MB, fully overwritten by the final GEMM)
    unsigned short* Wvt = (unsigned short*)d_out;                       // 2 MB
    unsigned short* Wlb = (unsigned short*)((char*)d_out + 2097152);    // 2 MB

    const size_t NEED = 2101248 + (size_t)M_TOT * KDIM * 2;
    hipLaunchKernelGGL(prep0_kernel, dim3(768), dim3(256), 0, stream,
                       Wv, Wlin, bv, blin, Wvt, Wlb, bcomb);
    if (ws_size >= NEED) {
        (void)hipFuncSetAttribute((const void*)main_8p,
                                  hipFuncAttributeMaxDynamicSharedMemorySize,
                                  131072);
        hipLaunchKernelGGL(prep1_kernel, dim3(256 + 2048), dim3(256), 0, stream,
                           Wlb, Wvt, xs, Wc, Xb);
        hipLaunchKernelGGL(main_8p, dim3(256), dim3(512), 131072, stream,
                           Xb, Wc, bcomb, out);
    } else {
        hipLaunchKernelGGL(prep1_kernel, dim3(256), dim3(256), 0, stream,
                           Wlb, Wvt, xs, Wc, Xb);
        hipLaunchKernelGGL(main_gemm_f32, dim3((M_TOT / 128) * (NDIM / 128)),
                           dim3(256), 0, stream, xs, Wc, bcomb, out);
    }
}